// Round 3
// baseline (257.582 us; speedup 1.0000x reference)
//
#include <hip/hip_runtime.h>

#define V 50000
#define E_DIM 256
#define H_DIM 512
#define H2 1024
#define G3 1536
#define BSZ 64
#define SEQ 200
#define KX 1280
#define MROWS 12800
#define NBLK_WO 782  // ceil(50000/64)

// ws offsets (float units)
#define XBF_OFF   0        // 64*1280 bf16
#define H0_OFF    40960    // 64*512 f32
#define H0BF_OFF  73728    // 64*512 bf16
#define GI_OFF    90112    // 64*1536 f32
#define GH_OFF    188416   // 64*1536 f32
#define STBF_OFF  286720   // 64*512 bf16
#define WCBF_OFF  303104   // 512*1024 bf16
#define SC_OFF    565248   // 12800 f32
#define REDG_OFF  578048   // 64*782*2 f32
#define RED_OFF   678144   // 64*2 f32

// d_out layout (floats)
#define OUT_STATE 3200000
#define OUT_W     3232768

typedef __attribute__((ext_vector_type(8))) short bf16x8;
typedef __attribute__((ext_vector_type(4))) float f32x4;

__device__ __forceinline__ float sigmf(float x) { return 1.f / (1.f + __expf(-x)); }

__device__ __forceinline__ ushort f2bf(float f) {
  uint u = __float_as_uint(f);
  uint r = (u + 0x7FFFu + ((u >> 16) & 1u)) >> 16;
  return (ushort)r;
}

__device__ __forceinline__ bf16x8 cvt8(float4 a, float4 b) {
  bf16x8 r;
  r[0] = (short)f2bf(a.x); r[1] = (short)f2bf(a.y);
  r[2] = (short)f2bf(a.z); r[3] = (short)f2bf(a.w);
  r[4] = (short)f2bf(b.x); r[5] = (short)f2bf(b.y);
  r[6] = (short)f2bf(b.z); r[7] = (short)f2bf(b.w);
  return r;
}

// ---------------- kprep: Wc f32->bf16 (blocks 0..511) + build x_bf/h0 (blocks 512..575)
__global__ void kprep(const float* __restrict__ Wc_W, ushort* __restrict__ Wc_bf,
                      const int* __restrict__ input_idx, const float* __restrict__ encoded,
                      const float* __restrict__ prev_state, const float* __restrict__ weighted,
                      const int* __restrict__ order_p, const float* __restrict__ embed_W,
                      const float* __restrict__ Ws_W, const float* __restrict__ Ws_b,
                      ushort* __restrict__ x_bf, float* __restrict__ h0,
                      ushort* __restrict__ h0_bf) {
  int bid = blockIdx.x, tid = threadIdx.x;
  if (bid < 512) {
    int i = bid * 256 + tid;  // 512*256 = 131072 float4s = 512*1024 floats
    float4 v = ((const float4*)Wc_W)[i];
    ushort4 o;
    o.x = f2bf(v.x); o.y = f2bf(v.y); o.z = f2bf(v.z); o.w = f2bf(v.w);
    ((ushort4*)Wc_bf)[i] = o;
    return;
  }
  int b = bid - 512;
  int order = order_p[0];
  int idx = input_idx[b];
  x_bf[b * KX + tid] = f2bf(embed_W[(size_t)idx * E_DIM + tid]);
  if (order != 0) {
    for (int j = tid; j < H2; j += 256) x_bf[b * KX + E_DIM + j] = f2bf(weighted[b * H2 + j]);
    for (int j = tid; j < H_DIM; j += 256) {
      float v = prev_state[b * H_DIM + j];
      h0[b * H_DIM + j] = v;
      h0_bf[b * H_DIM + j] = f2bf(v);
    }
  } else {
    for (int j = tid; j < H2; j += 256) x_bf[b * KX + E_DIM + j] = 0;
    const float* er = encoded + ((size_t)b * SEQ + 1) * H2;
    for (int j = tid; j < H_DIM; j += 256) {
      float acc = Ws_b[j];
      const float* wr = Ws_W + (size_t)j * H2;
      for (int k = 0; k < H2; ++k) acc = fmaf(er[k], wr[k], acc);
      h0[b * H_DIM + j] = acc;
      h0_bf[b * H_DIM + j] = f2bf(acc);
    }
  }
}

// ---------------- shared GEMM body: out[m][n] = A[m][:] . W[n][:] + bias[n]
// A: [64][kdim] bf16. W: [N][kdim] f32 (cvt on the fly). Wave owns 16 n, all 64 m.
// EPI: per-block online (max, sumexp) row partials -> redg[row][bid].
template <bool EPI>
__device__ __forceinline__ void gemm_body(const ushort* __restrict__ Abf,
                                          const float* __restrict__ W,
                                          const float* __restrict__ bias,
                                          float* __restrict__ out, int N, int kdim,
                                          float* __restrict__ redg, int bid) {
  int tid = threadIdx.x;
  int lane = tid & 63, wv = tid >> 6;
  int l15 = lane & 15, lg = lane >> 4;
  int n0 = (bid * 4 + wv) * 16;
  int col = n0 + l15;
  bool valid = col < N;
  int colc = valid ? col : N - 1;
  f32x4 acc[4];
#pragma unroll
  for (int mt = 0; mt < 4; ++mt) acc[mt] = (f32x4){0.f, 0.f, 0.f, 0.f};
  const float* wrow = W + (size_t)colc * kdim + lg * 8;
  const ushort* arow = Abf + (size_t)l15 * kdim + lg * 8;
#pragma unroll 2
  for (int k0 = 0; k0 < kdim; k0 += 32) {
    float4 w0 = *(const float4*)(wrow + k0);
    float4 w1 = *(const float4*)(wrow + k0 + 4);
    bf16x8 bf = cvt8(w0, w1);
#pragma unroll
    for (int mt = 0; mt < 4; ++mt) {
      bf16x8 af = *(const bf16x8*)(arow + (size_t)mt * 16 * kdim + k0);
      acc[mt] = __builtin_amdgcn_mfma_f32_16x16x32_bf16(af, bf, acc[mt], 0, 0, 0);
    }
  }
  float bv = bias[colc];
  if (valid) {
#pragma unroll
    for (int mt = 0; mt < 4; ++mt)
#pragma unroll
      for (int r = 0; r < 4; ++r)
        out[(size_t)(mt * 16 + lg * 4 + r) * N + col] = acc[mt][r] + bv;
  }
  if constexpr (EPI) {
    __shared__ float sm[4][64], ss[4][64];
#pragma unroll
    for (int mt = 0; mt < 4; ++mt)
#pragma unroll
      for (int r = 0; r < 4; ++r) {
        float v = valid ? acc[mt][r] + bv : -1e30f;
        float mx = v;
#pragma unroll
        for (int off = 1; off < 16; off <<= 1) mx = fmaxf(mx, __shfl_xor(mx, off, 64));
        float e = valid ? __expf(v - mx) : 0.f;
#pragma unroll
        for (int off = 1; off < 16; off <<= 1) e += __shfl_xor(e, off, 64);
        if (l15 == 0) {
          sm[wv][mt * 16 + lg * 4 + r] = mx;
          ss[wv][mt * 16 + lg * 4 + r] = e;
        }
      }
    __syncthreads();
    if (tid < 64) {
      float M = -1e30f, S = 0.f;
#pragma unroll
      for (int w = 0; w < 4; ++w) {
        float m2 = sm[w][tid], s2 = ss[w][tid];
        float mn = fmaxf(M, m2);
        S = S * __expf(M - mn) + s2 * __expf(m2 - mn);
        M = mn;
      }
      redg[((size_t)tid * NBLK_WO + bid) * 2] = M;
      redg[((size_t)tid * NBLK_WO + bid) * 2 + 1] = S;
    }
  }
}

// gi/gh fused (grid.y selects)
__global__ __launch_bounds__(256) void mfma_gates(const ushort* __restrict__ x_bf,
                                                  const float* __restrict__ Wih,
                                                  const float* __restrict__ bih,
                                                  const ushort* __restrict__ h0_bf,
                                                  const float* __restrict__ Whh,
                                                  const float* __restrict__ bhh,
                                                  float* __restrict__ gi, float* __restrict__ gh) {
  if (blockIdx.y == 0)
    gemm_body<false>(x_bf, Wih, bih, gi, G3, KX, nullptr, blockIdx.x);
  else
    gemm_body<false>(h0_bf, Whh, bhh, gh, G3, H_DIM, nullptr, blockIdx.x);
}

// Wo GEMM + softmax partials
__global__ __launch_bounds__(256) void mfma_wo(const ushort* __restrict__ state_bf,
                                               const float* __restrict__ Wo_W,
                                               const float* __restrict__ Wo_b,
                                               float* __restrict__ out,
                                               float* __restrict__ redg) {
  gemm_body<true>(state_bf, Wo_W, Wo_b, out, V, H_DIM, redg, blockIdx.x);
}

// ---------------- K2: GRU cell -> state f32 (d_out) + bf16 (ws)
__global__ void k2_gru(const float* __restrict__ gi, const float* __restrict__ gh,
                       const float* __restrict__ h0, float* __restrict__ state_out,
                       ushort* __restrict__ state_bf) {
  int b = blockIdx.x, j = threadIdx.x;  // block = 512
  float ir = gi[b * G3 + j], iz = gi[b * G3 + H_DIM + j], inn = gi[b * G3 + 2 * H_DIM + j];
  float hr = gh[b * G3 + j], hz = gh[b * G3 + H_DIM + j], hn = gh[b * G3 + 2 * H_DIM + j];
  float r = sigmf(ir + hr);
  float z = sigmf(iz + hz);
  float n = tanhf(inn + r * hn);
  float st = (1.f - z) * n + z * h0[b * H_DIM + j];
  state_out[b * H_DIM + j] = st;
  state_bf[b * H_DIM + j] = f2bf(st);
}

// ---------------- K4: score_c[m] = sum_n tanh((enc@WcT)[m][n]+b[n]) * state[b][n]
// 512 thr = 8 waves = 2 m-groups x 4 n-groups; wave = 16 rows x 128 n; B direct from L2.
__global__ __launch_bounds__(512) void k4_mfma2(const float* __restrict__ encoded,
                                                const ushort* __restrict__ Wc_bf,
                                                const float* __restrict__ Wc_b,
                                                const float* __restrict__ state,
                                                float* __restrict__ score_c) {
  int tid = threadIdx.x, lane = tid & 63, wv = tid >> 6;
  int l15 = lane & 15, lg = lane >> 4;
  int mgrp = wv >> 2, ngrp = wv & 3;
  int m0w = blockIdx.x * 32 + mgrp * 16;
  int nbase = ngrp * 128;
  f32x4 acc[8];
#pragma unroll
  for (int nt = 0; nt < 8; ++nt) acc[nt] = (f32x4){0.f, 0.f, 0.f, 0.f};
  const float* arow = encoded + (size_t)(m0w + l15) * H2 + lg * 8;
  const ushort* brow = Wc_bf + (size_t)(nbase + l15) * H2 + lg * 8;
#pragma unroll 2
  for (int k0 = 0; k0 < H2; k0 += 32) {
    float4 a0 = *(const float4*)(arow + k0);
    float4 a1 = *(const float4*)(arow + k0 + 4);
    bf16x8 af = cvt8(a0, a1);
#pragma unroll
    for (int nt = 0; nt < 8; ++nt) {
      bf16x8 bf = *(const bf16x8*)(brow + (size_t)nt * 16 * H2 + k0);
      acc[nt] = __builtin_amdgcn_mfma_f32_16x16x32_bf16(af, bf, acc[nt], 0, 0, 0);
    }
  }
  // epilogue: tanh(+bias)*state, reduce n within wave then across n-group waves
  float pv[4] = {0.f, 0.f, 0.f, 0.f};
#pragma unroll
  for (int nt = 0; nt < 8; ++nt) {
    int n = nbase + nt * 16 + l15;
    float bias = Wc_b[n];
#pragma unroll
    for (int r = 0; r < 4; ++r) {
      int m = m0w + lg * 4 + r;
      int b = m / SEQ;
      pv[r] += tanhf(acc[nt][r] + bias) * state[b * H_DIM + n];
    }
  }
#pragma unroll
  for (int off = 1; off < 16; off <<= 1)
#pragma unroll
    for (int r = 0; r < 4; ++r) pv[r] += __shfl_xor(pv[r], off, 64);
  __shared__ float scred[8][16];
  if (l15 == 0) {
#pragma unroll
    for (int r = 0; r < 4; ++r) scred[wv][lg * 4 + r] = pv[r];
  }
  __syncthreads();
  if (tid < 32) {
    int mg = tid >> 4, r16 = tid & 15;
    float t = scred[mg * 4 + 0][r16] + scred[mg * 4 + 1][r16] +
              scred[mg * 4 + 2][r16] + scred[mg * 4 + 3][r16];
    score_c[blockIdx.x * 32 + mg * 16 + r16] = t;
  }
}

// ---------------- kred: combine redg partials + score_c tail -> red[b] = (max, sum)
__global__ void kred(const float* __restrict__ redg, const float* __restrict__ score_c,
                     const int* __restrict__ eidx, float* __restrict__ red) {
  int b = blockIdx.x, tid = threadIdx.x;
  float m = -1e30f, s = 0.f;
  for (int i = tid; i < NBLK_WO; i += 256) {
    float m2 = redg[((size_t)b * NBLK_WO + i) * 2];
    float s2 = redg[((size_t)b * NBLK_WO + i) * 2 + 1];
    float mn = fmaxf(m, m2);
    s = s * __expf(m - mn) + s2 * __expf(m2 - mn);
    m = mn;
  }
  for (int i = tid; i < SEQ; i += 256) {
    int ei = eidx[b * SEQ + i];
    float sc = tanhf(score_c[b * SEQ + i] + (ei == 0 ? -1000.f : 0.f));
    float mn = fmaxf(m, sc);
    s = s * __expf(m - mn) + __expf(sc - mn);
    m = mn;
  }
  __shared__ float ms[256], ssh[256];
  ms[tid] = m; ssh[tid] = s;
  __syncthreads();
  for (int off = 128; off > 0; off >>= 1) {
    if (tid < off) {
      float m2 = ms[tid + off], s2 = ssh[tid + off];
      float mn = fmaxf(ms[tid], m2);
      ssh[tid] = ssh[tid] * __expf(ms[tid] - mn) + s2 * __expf(m2 - mn);
      ms[tid] = mn;
    }
    __syncthreads();
  }
  if (tid == 0) {
    red[b * 2] = ms[0];
    red[b * 2 + 1] = ssh[0];
  }
}

// ---------------- K7: score_g -> prob_g in place
__global__ void k7_probs(float* __restrict__ sg, const float* __restrict__ red) {
  int i = blockIdx.x * 256 + threadIdx.x;
  int b = i / 12500;
  float mm = red[b * 2], rd = 1.f / red[b * 2 + 1];
  float4* p = (float4*)sg;
  float4 v = p[i];
  v.x = __expf(v.x - mm) * rd;
  v.y = __expf(v.y - mm) * rd;
  v.z = __expf(v.z - mm) * rd;
  v.w = __expf(v.w - mm) * rd;
  p[i] = v;
}

// ---------------- K8: prob_c scatter-add + match-attn weighted sum
__global__ void k8_copy(const float* __restrict__ score_c, const int* __restrict__ eidx,
                        const int* __restrict__ input_idx, const float* __restrict__ red,
                        const float* __restrict__ encoded, float* __restrict__ out,
                        float* __restrict__ wout) {
  int b = blockIdx.x, tid = threadIdx.x;
  __shared__ float att_s[SEQ];
  __shared__ int cnt_s[256];
  float mm = red[b * 2], rd = 1.f / red[b * 2 + 1];
  int inp = input_idx[b];
  int cnt = 0;
  for (int s = tid; s < SEQ; s += 256) {
    int ei = eidx[b * SEQ + s];
    float sc = tanhf(score_c[b * SEQ + s] + (ei == 0 ? -1000.f : 0.f));
    float p = __expf(sc - mm) * rd;
    bool mt = (ei == inp);
    att_s[s] = mt ? p : 0.f;
    cnt += mt ? 1 : 0;
    atomicAdd(&out[(size_t)b * V + ei], p);
  }
  cnt_s[tid] = cnt;
  __syncthreads();
  for (int off = 128; off > 0; off >>= 1) {
    if (tid < off) cnt_s[tid] += cnt_s[tid + off];
    __syncthreads();
  }
  int c = cnt_s[0];
  float scale = (c > 1) ? 1.f / (float)c : 1.f;
  float w0 = 0, w1 = 0, w2 = 0, w3 = 0;
  for (int s = 0; s < SEQ; ++s) {
    float a = att_s[s];
    if (a != 0.f) {
      const float* er = encoded + ((size_t)b * SEQ + s) * H2;
      w0 += a * er[tid];
      w1 += a * er[tid + 256];
      w2 += a * er[tid + 512];
      w3 += a * er[tid + 768];
    }
  }
  wout[b * H2 + tid] = w0 * scale;
  wout[b * H2 + tid + 256] = w1 * scale;
  wout[b * H2 + tid + 512] = w2 * scale;
  wout[b * H2 + tid + 768] = w3 * scale;
}

extern "C" void kernel_launch(void* const* d_in, const int* in_sizes, int n_in,
                              void* d_out, int out_size, void* d_ws, size_t ws_size,
                              hipStream_t stream) {
  const int* input_idx = (const int*)d_in[0];
  const float* encoded = (const float*)d_in[1];
  const int* encoded_idx = (const int*)d_in[2];
  const float* prev_state = (const float*)d_in[3];
  const float* weighted = (const float*)d_in[4];
  const int* order_p = (const int*)d_in[5];
  const float* embed_W = (const float*)d_in[6];
  const float* Wih = (const float*)d_in[7];
  const float* Whh = (const float*)d_in[8];
  const float* bih = (const float*)d_in[9];
  const float* bhh = (const float*)d_in[10];
  const float* Ws_W = (const float*)d_in[11];
  const float* Ws_b = (const float*)d_in[12];
  const float* Wo_W = (const float*)d_in[13];
  const float* Wo_b = (const float*)d_in[14];
  const float* Wc_W = (const float*)d_in[15];
  const float* Wc_b = (const float*)d_in[16];

  float* ws = (float*)d_ws;
  float* out = (float*)d_out;
  ushort* x_bf = (ushort*)(ws + XBF_OFF);
  float* h0 = ws + H0_OFF;
  ushort* h0_bf = (ushort*)(ws + H0BF_OFF);
  float* gi = ws + GI_OFF;
  float* gh = ws + GH_OFF;
  ushort* state_bf = (ushort*)(ws + STBF_OFF);
  ushort* Wc_bf = (ushort*)(ws + WCBF_OFF);
  float* score_c = ws + SC_OFF;
  float* redg = ws + REDG_OFF;
  float* red = ws + RED_OFF;
  float* state = out + OUT_STATE;
  float* wout = out + OUT_W;

  kprep<<<576, 256, 0, stream>>>(Wc_W, Wc_bf, input_idx, encoded, prev_state, weighted,
                                 order_p, embed_W, Ws_W, Ws_b, x_bf, h0, h0_bf);
  mfma_gates<<<dim3(24, 2), 256, 0, stream>>>(x_bf, Wih, bih, h0_bf, Whh, bhh, gi, gh);
  k2_gru<<<64, 512, 0, stream>>>(gi, gh, h0, state, state_bf);
  mfma_wo<<<NBLK_WO, 256, 0, stream>>>(state_bf, Wo_W, Wo_b, out, redg);
  k4_mfma2<<<400, 512, 0, stream>>>(encoded, Wc_bf, Wc_b, state, score_c);
  kred<<<64, 256, 0, stream>>>(redg, score_c, encoded_idx, red);
  k7_probs<<<3125, 256, 0, stream>>>(out, red);
  k8_copy<<<64, 256, 0, stream>>>(score_c, encoded_idx, input_idx, red, encoded, out, wout);
}

// Round 4
// 203.358 us; speedup vs baseline: 1.2666x; 1.2666x over previous
//
#include <hip/hip_runtime.h>

#define V 50000
#define E_DIM 256
#define H_DIM 512
#define H2 1024
#define G3 1536
#define BSZ 64
#define SEQ 200
#define KX 1280
#define MROWS 12800
#define NBLK_WO 782  // ceil(50000/64)

// ws offsets (float units)
#define XBF_OFF   0        // 64*1280 bf16
#define H0_OFF    40960    // 64*512 f32
#define H0BF_OFF  73728    // 64*512 bf16
#define GI_OFF    90112    // 64*1536 f32
#define GH_OFF    188416   // 64*1536 f32
#define STBF_OFF  286720   // 64*512 bf16
#define WCBF_OFF  303104   // 512*1024 bf16
#define SC_OFF    565248   // 12800 f32
#define REDG_OFF  578048   // 64*782*2 f32
#define RED_OFF   678144   // 64*2 f32

// d_out layout (floats)
#define OUT_STATE 3200000
#define OUT_W     3232768

typedef __attribute__((ext_vector_type(8))) short bf16x8;
typedef __attribute__((ext_vector_type(4))) float f32x4;

__device__ __forceinline__ float sigmf(float x) { return 1.f / (1.f + __expf(-x)); }

__device__ __forceinline__ ushort f2bf(float f) {
  uint u = __float_as_uint(f);
  uint r = (u + 0x7FFFu + ((u >> 16) & 1u)) >> 16;
  return (ushort)r;
}

__device__ __forceinline__ float tanhfast(float x) {
  float xc = fminf(15.f, fmaxf(-15.f, x));
  float e = __expf(2.f * xc);
  return (e - 1.f) * __builtin_amdgcn_rcpf(e + 1.f);
}

__device__ __forceinline__ bf16x8 cvt8(float4 a, float4 b) {
  bf16x8 r;
  r[0] = (short)f2bf(a.x); r[1] = (short)f2bf(a.y);
  r[2] = (short)f2bf(a.z); r[3] = (short)f2bf(a.w);
  r[4] = (short)f2bf(b.x); r[5] = (short)f2bf(b.y);
  r[6] = (short)f2bf(b.z); r[7] = (short)f2bf(b.w);
  return r;
}

// ---------------- kprep: Wc f32->bf16 (blocks 0..511) + build x_bf/h0 (blocks 512..575)
__global__ void kprep(const float* __restrict__ Wc_W, ushort* __restrict__ Wc_bf,
                      const int* __restrict__ input_idx, const float* __restrict__ encoded,
                      const float* __restrict__ prev_state, const float* __restrict__ weighted,
                      const int* __restrict__ order_p, const float* __restrict__ embed_W,
                      const float* __restrict__ Ws_W, const float* __restrict__ Ws_b,
                      ushort* __restrict__ x_bf, float* __restrict__ h0,
                      ushort* __restrict__ h0_bf) {
  int bid = blockIdx.x, tid = threadIdx.x;
  if (bid < 512) {
    int i = bid * 256 + tid;  // 512*256 float4s = 512*1024 floats
    float4 v = ((const float4*)Wc_W)[i];
    ushort4 o;
    o.x = f2bf(v.x); o.y = f2bf(v.y); o.z = f2bf(v.z); o.w = f2bf(v.w);
    ((ushort4*)Wc_bf)[i] = o;
    return;
  }
  int b = bid - 512;
  int order = order_p[0];
  int idx = input_idx[b];
  x_bf[b * KX + tid] = f2bf(embed_W[(size_t)idx * E_DIM + tid]);
  if (order != 0) {
    for (int j = tid; j < H2; j += 256) x_bf[b * KX + E_DIM + j] = f2bf(weighted[b * H2 + j]);
    for (int j = tid; j < H_DIM; j += 256) {
      float v = prev_state[b * H_DIM + j];
      h0[b * H_DIM + j] = v;
      h0_bf[b * H_DIM + j] = f2bf(v);
    }
  } else {
    for (int j = tid; j < H2; j += 256) x_bf[b * KX + E_DIM + j] = 0;
    const float* er = encoded + ((size_t)b * SEQ + 1) * H2;
    for (int j = tid; j < H_DIM; j += 256) {
      float acc = Ws_b[j];
      const float* wr = Ws_W + (size_t)j * H2;
      for (int k = 0; k < H2; ++k) acc = fmaf(er[k], wr[k], acc);
      h0[b * H_DIM + j] = acc;
      h0_bf[b * H_DIM + j] = f2bf(acc);
    }
  }
}

// ---------------- shared GEMM body: out[m][n] = A[m][:] . W[n][:] + bias[n]
// A: [64][kdim] bf16. W: [N][kdim] f32 (cvt on the fly). Wave owns 16 n, all 64 m.
template <bool EPI>
__device__ __forceinline__ void gemm_body(const ushort* __restrict__ Abf,
                                          const float* __restrict__ W,
                                          const float* __restrict__ bias,
                                          float* __restrict__ out, int N, int kdim,
                                          float* __restrict__ redg, int bid) {
  int tid = threadIdx.x;
  int lane = tid & 63, wv = tid >> 6;
  int l15 = lane & 15, lg = lane >> 4;
  int n0 = (bid * 4 + wv) * 16;
  int col = n0 + l15;
  bool valid = col < N;
  int colc = valid ? col : N - 1;
  f32x4 acc[4];
#pragma unroll
  for (int mt = 0; mt < 4; ++mt) acc[mt] = (f32x4){0.f, 0.f, 0.f, 0.f};
  const float* wrow = W + (size_t)colc * kdim + lg * 8;
  const ushort* arow = Abf + (size_t)l15 * kdim + lg * 8;
#pragma unroll 4
  for (int k0 = 0; k0 < kdim; k0 += 32) {
    float4 w0 = *(const float4*)(wrow + k0);
    float4 w1 = *(const float4*)(wrow + k0 + 4);
    bf16x8 bf = cvt8(w0, w1);
#pragma unroll
    for (int mt = 0; mt < 4; ++mt) {
      bf16x8 af = *(const bf16x8*)(arow + (size_t)mt * 16 * kdim + k0);
      acc[mt] = __builtin_amdgcn_mfma_f32_16x16x32_bf16(af, bf, acc[mt], 0, 0, 0);
    }
  }
  float bv = bias[colc];
  if (valid) {
#pragma unroll
    for (int mt = 0; mt < 4; ++mt)
#pragma unroll
      for (int r = 0; r < 4; ++r)
        out[(size_t)(mt * 16 + lg * 4 + r) * N + col] = acc[mt][r] + bv;
  }
  if constexpr (EPI) {
    __shared__ float sm[4][64], ss[4][64];
#pragma unroll
    for (int mt = 0; mt < 4; ++mt)
#pragma unroll
      for (int r = 0; r < 4; ++r) {
        float v = valid ? acc[mt][r] + bv : -1e30f;
        float mx = v;
#pragma unroll
        for (int off = 1; off < 16; off <<= 1) mx = fmaxf(mx, __shfl_xor(mx, off, 64));
        float e = valid ? __expf(v - mx) : 0.f;
#pragma unroll
        for (int off = 1; off < 16; off <<= 1) e += __shfl_xor(e, off, 64);
        if (l15 == 0) {
          sm[wv][mt * 16 + lg * 4 + r] = mx;
          ss[wv][mt * 16 + lg * 4 + r] = e;
        }
      }
    __syncthreads();
    if (tid < 64) {
      float M = -1e30f, S = 0.f;
#pragma unroll
      for (int w = 0; w < 4; ++w) {
        float m2 = sm[w][tid], s2 = ss[w][tid];
        float mn = fmaxf(M, m2);
        S = S * __expf(M - mn) + s2 * __expf(m2 - mn);
        M = mn;
      }
      redg[((size_t)tid * NBLK_WO + bid) * 2] = M;
      redg[((size_t)tid * NBLK_WO + bid) * 2 + 1] = S;
    }
  }
}

// gi/gh fused (grid.y selects)
__global__ __launch_bounds__(256) void mfma_gates(const ushort* __restrict__ x_bf,
                                                  const float* __restrict__ Wih,
                                                  const float* __restrict__ bih,
                                                  const ushort* __restrict__ h0_bf,
                                                  const float* __restrict__ Whh,
                                                  const float* __restrict__ bhh,
                                                  float* __restrict__ gi, float* __restrict__ gh) {
  if (blockIdx.y == 0)
    gemm_body<false>(x_bf, Wih, bih, gi, G3, KX, nullptr, blockIdx.x);
  else
    gemm_body<false>(h0_bf, Whh, bhh, gh, G3, H_DIM, nullptr, blockIdx.x);
}

// Wo GEMM + softmax partials
__global__ __launch_bounds__(256) void mfma_wo(const ushort* __restrict__ state_bf,
                                               const float* __restrict__ Wo_W,
                                               const float* __restrict__ Wo_b,
                                               float* __restrict__ out,
                                               float* __restrict__ redg) {
  gemm_body<true>(state_bf, Wo_W, Wo_b, out, V, H_DIM, redg, blockIdx.x);
}

// ---------------- K2: GRU cell -> state f32 (d_out) + bf16 (ws)
__global__ void k2_gru(const float* __restrict__ gi, const float* __restrict__ gh,
                       const float* __restrict__ h0, float* __restrict__ state_out,
                       ushort* __restrict__ state_bf) {
  int b = blockIdx.x, j = threadIdx.x;  // block = 512
  float ir = gi[b * G3 + j], iz = gi[b * G3 + H_DIM + j], inn = gi[b * G3 + 2 * H_DIM + j];
  float hr = gh[b * G3 + j], hz = gh[b * G3 + H_DIM + j], hn = gh[b * G3 + 2 * H_DIM + j];
  float r = sigmf(ir + hr);
  float z = sigmf(iz + hz);
  float n = tanhf(inn + r * hn);
  float st = (1.f - z) * n + z * h0[b * H_DIM + j];
  state_out[b * H_DIM + j] = st;
  state_bf[b * H_DIM + j] = f2bf(st);
}

// ---------------- K4 v3: score_c[m] = sum_n tanh((enc@WcT)[m][n]+b[n]) * state[b][n]
// 512 thr = 8 waves; m-tile 64; wave = 4 m-frags x 64-col n-group (16 MFMA / 4 LDS reads
// per kstep). B staged frag-major in LDS (conflict-free), double-buffered.
__global__ __launch_bounds__(512) void k4_mfma3(const float* __restrict__ encoded,
                                                const ushort* __restrict__ Wc_bf,
                                                const float* __restrict__ Wc_b,
                                                const float* __restrict__ state,
                                                float* __restrict__ score_c) {
  __shared__ ushort Bs[2][512 * 32];  // frag-major: frag f(0..31) | lane | 8 ushorts
  __shared__ float scred[8][64];
  int tid = threadIdx.x, lane = tid & 63, wv = tid >> 6;
  int l15 = lane & 15, lg = lane >> 4;
  int m0 = blockIdx.x * 64;
  f32x4 acc[4][4];
#pragma unroll
  for (int mt = 0; mt < 4; ++mt)
#pragma unroll
    for (int j = 0; j < 4; ++j) acc[mt][j] = (f32x4){0.f, 0.f, 0.f, 0.f};

  // staging: thread t handles chunks (n = t>>2 + q*128, lgc = t&3), q=0..3
  const int sn = tid >> 2, slg = tid & 3;
  const ushort* gsrc = Wc_bf + (size_t)sn * H2 + slg * 8;
  const int slotbase = (sn >> 4) * 64 + slg * 16 + (sn & 15);  // 16B units; +q*512
  const float* aptr = encoded + (size_t)(m0 + l15) * H2 + lg * 8;

  bf16x8 g[4];
#pragma unroll
  for (int q = 0; q < 4; ++q) g[q] = *(const bf16x8*)(gsrc + (size_t)q * 128 * H2);
#pragma unroll
  for (int q = 0; q < 4; ++q) *(bf16x8*)&Bs[0][(slotbase + q * 512) * 8] = g[q];
  __syncthreads();

  for (int ks = 0; ks < 32; ++ks) {
    int cur = ks & 1;
    if (ks < 31) {
      int k0n = (ks + 1) * 32;
#pragma unroll
      for (int q = 0; q < 4; ++q)
        g[q] = *(const bf16x8*)(gsrc + (size_t)q * 128 * H2 + k0n);
    }
    int k0 = ks * 32;
    bf16x8 af[4];
#pragma unroll
    for (int mt = 0; mt < 4; ++mt) {
      float4 a0 = *(const float4*)(aptr + (size_t)mt * 16 * H2 + k0);
      float4 a1 = *(const float4*)(aptr + (size_t)mt * 16 * H2 + k0 + 4);
      af[mt] = cvt8(a0, a1);
    }
#pragma unroll
    for (int j = 0; j < 4; ++j) {
      bf16x8 bf = *(const bf16x8*)&Bs[cur][((wv * 4 + j) * 64 + lane) * 8];
#pragma unroll
      for (int mt = 0; mt < 4; ++mt)
        acc[mt][j] = __builtin_amdgcn_mfma_f32_16x16x32_bf16(af[mt], bf, acc[mt][j], 0, 0, 0);
    }
    if (ks < 31) {
#pragma unroll
      for (int q = 0; q < 4; ++q) *(bf16x8*)&Bs[cur ^ 1][(slotbase + q * 512) * 8] = g[q];
    }
    __syncthreads();
  }

  // epilogue: tanh(+bias)*state, reduce over n
  float pv[4][4];
#pragma unroll
  for (int mt = 0; mt < 4; ++mt)
#pragma unroll
    for (int r = 0; r < 4; ++r) pv[mt][r] = 0.f;
#pragma unroll
  for (int j = 0; j < 4; ++j) {
    int n = wv * 64 + j * 16 + l15;
    float bias = Wc_b[n];
#pragma unroll
    for (int mt = 0; mt < 4; ++mt) {
      int mrow = m0 + mt * 16 + lg * 4;
#pragma unroll
      for (int r = 0; r < 4; ++r) {
        int b = (mrow + r) / SEQ;
        pv[mt][r] += tanhfast(acc[mt][j][r] + bias) * state[b * H_DIM + n];
      }
    }
  }
#pragma unroll
  for (int off = 1; off < 16; off <<= 1)
#pragma unroll
    for (int mt = 0; mt < 4; ++mt)
#pragma unroll
      for (int r = 0; r < 4; ++r) pv[mt][r] += __shfl_xor(pv[mt][r], off, 64);
  if (l15 == 0) {
#pragma unroll
    for (int mt = 0; mt < 4; ++mt)
#pragma unroll
      for (int r = 0; r < 4; ++r) scred[wv][mt * 16 + lg * 4 + r] = pv[mt][r];
  }
  __syncthreads();
  if (tid < 64) {
    float s = 0.f;
#pragma unroll
    for (int w = 0; w < 8; ++w) s += scred[w][tid];
    score_c[m0 + tid] = s;
  }
}

// ---------------- kred: combine redg partials + score_c tail -> red[b] = (max, sum)
__global__ void kred(const float* __restrict__ redg, const float* __restrict__ score_c,
                     const int* __restrict__ eidx, float* __restrict__ red) {
  int b = blockIdx.x, tid = threadIdx.x;
  float m = -1e30f, s = 0.f;
  for (int i = tid; i < NBLK_WO; i += 256) {
    float m2 = redg[((size_t)b * NBLK_WO + i) * 2];
    float s2 = redg[((size_t)b * NBLK_WO + i) * 2 + 1];
    float mn = fmaxf(m, m2);
    s = s * __expf(m - mn) + s2 * __expf(m2 - mn);
    m = mn;
  }
  for (int i = tid; i < SEQ; i += 256) {
    int ei = eidx[b * SEQ + i];
    float sc = tanhf(score_c[b * SEQ + i] + (ei == 0 ? -1000.f : 0.f));
    float mn = fmaxf(m, sc);
    s = s * __expf(m - mn) + __expf(sc - mn);
    m = mn;
  }
  __shared__ float ms[256], ssh[256];
  ms[tid] = m; ssh[tid] = s;
  __syncthreads();
  for (int off = 128; off > 0; off >>= 1) {
    if (tid < off) {
      float m2 = ms[tid + off], s2 = ssh[tid + off];
      float mn = fmaxf(ms[tid], m2);
      ssh[tid] = ssh[tid] * __expf(ms[tid] - mn) + s2 * __expf(m2 - mn);
      ms[tid] = mn;
    }
    __syncthreads();
  }
  if (tid == 0) {
    red[b * 2] = ms[0];
    red[b * 2 + 1] = ssh[0];
  }
}

// ---------------- K7: score_g -> prob_g in place
__global__ void k7_probs(float* __restrict__ sg, const float* __restrict__ red) {
  int i = blockIdx.x * 256 + threadIdx.x;
  int b = i / 12500;
  float mm = red[b * 2], rd = 1.f / red[b * 2 + 1];
  float4* p = (float4*)sg;
  float4 v = p[i];
  v.x = __expf(v.x - mm) * rd;
  v.y = __expf(v.y - mm) * rd;
  v.z = __expf(v.z - mm) * rd;
  v.w = __expf(v.w - mm) * rd;
  p[i] = v;
}

// ---------------- K8: prob_c scatter-add + match-attn weighted sum
__global__ void k8_copy(const float* __restrict__ score_c, const int* __restrict__ eidx,
                        const int* __restrict__ input_idx, const float* __restrict__ red,
                        const float* __restrict__ encoded, float* __restrict__ out,
                        float* __restrict__ wout) {
  int b = blockIdx.x, tid = threadIdx.x;
  __shared__ float att_s[SEQ];
  __shared__ int cnt_s[256];
  float mm = red[b * 2], rd = 1.f / red[b * 2 + 1];
  int inp = input_idx[b];
  int cnt = 0;
  for (int s = tid; s < SEQ; s += 256) {
    int ei = eidx[b * SEQ + s];
    float sc = tanhf(score_c[b * SEQ + s] + (ei == 0 ? -1000.f : 0.f));
    float p = __expf(sc - mm) * rd;
    bool mt = (ei == inp);
    att_s[s] = mt ? p : 0.f;
    cnt += mt ? 1 : 0;
    atomicAdd(&out[(size_t)b * V + ei], p);
  }
  cnt_s[tid] = cnt;
  __syncthreads();
  for (int off = 128; off > 0; off >>= 1) {
    if (tid < off) cnt_s[tid] += cnt_s[tid + off];
    __syncthreads();
  }
  int c = cnt_s[0];
  float scale = (c > 1) ? 1.f / (float)c : 1.f;
  float w0 = 0, w1 = 0, w2 = 0, w3 = 0;
  for (int s = 0; s < SEQ; ++s) {
    float a = att_s[s];
    if (a != 0.f) {
      const float* er = encoded + ((size_t)b * SEQ + s) * H2;
      w0 += a * er[tid];
      w1 += a * er[tid + 256];
      w2 += a * er[tid + 512];
      w3 += a * er[tid + 768];
    }
  }
  wout[b * H2 + tid] = w0 * scale;
  wout[b * H2 + tid + 256] = w1 * scale;
  wout[b * H2 + tid + 512] = w2 * scale;
  wout[b * H2 + tid + 768] = w3 * scale;
}

extern "C" void kernel_launch(void* const* d_in, const int* in_sizes, int n_in,
                              void* d_out, int out_size, void* d_ws, size_t ws_size,
                              hipStream_t stream) {
  const int* input_idx = (const int*)d_in[0];
  const float* encoded = (const float*)d_in[1];
  const int* encoded_idx = (const int*)d_in[2];
  const float* prev_state = (const float*)d_in[3];
  const float* weighted = (const float*)d_in[4];
  const int* order_p = (const int*)d_in[5];
  const float* embed_W = (const float*)d_in[6];
  const float* Wih = (const float*)d_in[7];
  const float* Whh = (const float*)d_in[8];
  const float* bih = (const float*)d_in[9];
  const float* bhh = (const float*)d_in[10];
  const float* Ws_W = (const float*)d_in[11];
  const float* Ws_b = (const float*)d_in[12];
  const float* Wo_W = (const float*)d_in[13];
  const float* Wo_b = (const float*)d_in[14];
  const float* Wc_W = (const float*)d_in[15];
  const float* Wc_b = (const float*)d_in[16];

  float* ws = (float*)d_ws;
  float* out = (float*)d_out;
  ushort* x_bf = (ushort*)(ws + XBF_OFF);
  float* h0 = ws + H0_OFF;
  ushort* h0_bf = (ushort*)(ws + H0BF_OFF);
  float* gi = ws + GI_OFF;
  float* gh = ws + GH_OFF;
  ushort* state_bf = (ushort*)(ws + STBF_OFF);
  ushort* Wc_bf = (ushort*)(ws + WCBF_OFF);
  float* score_c = ws + SC_OFF;
  float* redg = ws + REDG_OFF;
  float* red = ws + RED_OFF;
  float* state = out + OUT_STATE;
  float* wout = out + OUT_W;

  kprep<<<576, 256, 0, stream>>>(Wc_W, Wc_bf, input_idx, encoded, prev_state, weighted,
                                 order_p, embed_W, Ws_W, Ws_b, x_bf, h0, h0_bf);
  mfma_gates<<<dim3(24, 2), 256, 0, stream>>>(x_bf, Wih, bih, h0_bf, Whh, bhh, gi, gh);
  k2_gru<<<64, 512, 0, stream>>>(gi, gh, h0, state, state_bf);
  mfma_wo<<<NBLK_WO, 256, 0, stream>>>(state_bf, Wo_W, Wo_b, out, redg);
  k4_mfma3<<<200, 512, 0, stream>>>(encoded, Wc_bf, Wc_b, state, score_c);
  kred<<<64, 256, 0, stream>>>(redg, score_c, encoded_idx, red);
  k7_probs<<<3125, 256, 0, stream>>>(out, red);
  k8_copy<<<64, 256, 0, stream>>>(score_c, encoded_idx, input_idx, red, encoded, out, wout);
}